// Round 7
// baseline (413.514 us; speedup 1.0000x reference)
//
#include <hip/hip_runtime.h>
#include <hip/hip_bf16.h>
#include <cstdint>
#include <math.h>

// Problem dims
#define BB 8
#define TT 1024
#define CC 768
#define HH 12
#define MROWS (BB*TT)   // 8192

typedef __hip_bfloat16 bf16;
typedef __attribute__((ext_vector_type(8))) __bf16 bf16x8;
typedef __attribute__((ext_vector_type(4))) float f32x4;

#define MFMA16(a,b,c) __builtin_amdgcn_mfma_f32_16x16x32_bf16(a,b,c,0,0,0)

// lgkm-only barrier: legal because the only outstanding vmem ops at the
// barrier are private register loads (not observable cross-thread). Avoids
// the compiler's s_waitcnt vmcnt(0) drain at __syncthreads.
__device__ __forceinline__ void lds_barrier() {
  asm volatile("s_waitcnt lgkmcnt(0)\n\ts_barrier" ::: "memory");
}

// ---------------- LayerNorm: f32 [rows][768] -> bf16 ----------------
__global__ __launch_bounds__(256) void ln_kernel(
    const float* __restrict__ x, const float* __restrict__ scale,
    const float* __restrict__ bias, bf16* __restrict__ out)
{
  int row = blockIdx.x;
  const float* xr = x + (size_t)row * CC;
  float v[3];
  float s = 0.f, s2 = 0.f;
  for (int i = 0; i < 3; i++) {
    v[i] = xr[threadIdx.x + i*256];
    s += v[i]; s2 += v[i]*v[i];
  }
  for (int m = 1; m < 64; m <<= 1) { s += __shfl_xor(s, m); s2 += __shfl_xor(s2, m); }
  __shared__ float ssum[4], ssum2[4];
  int w = threadIdx.x >> 6;
  if ((threadIdx.x & 63) == 0) { ssum[w] = s; ssum2[w] = s2; }
  __syncthreads();
  s = ssum[0]+ssum[1]+ssum[2]+ssum[3];
  s2 = ssum2[0]+ssum2[1]+ssum2[2]+ssum2[3];
  float mu = s * (1.f/CC);
  float var = s2 * (1.f/CC) - mu*mu;
  float rs = rsqrtf(var + 1e-5f);
  bf16* orow = out + (size_t)row * CC;
  for (int i = 0; i < 3; i++) {
    int c = threadIdx.x + i*256;
    orow[c] = __float2bfloat16((v[i]-mu)*rs*scale[c] + bias[c]);
  }
}

// ------------- weight transpose-cast: src f32 [K][N] -> dst bf16 [N][K] -------------
__global__ __launch_bounds__(256) void wtrans_kernel(
    const float* __restrict__ src, bf16* __restrict__ dst, int K, int N)
{
  __shared__ float tile[32][33];
  int n0 = blockIdx.x * 32, k0 = blockIdx.y * 32;
  int tx = threadIdx.x & 31, ty = threadIdx.x >> 5;   // ty 0..7
  for (int i = 0; i < 4; i++)
    tile[ty + i*8][tx] = src[(size_t)(k0 + ty + i*8)*N + n0 + tx];
  __syncthreads();
  for (int i = 0; i < 4; i++)
    dst[(size_t)(n0 + ty + i*8)*K + k0 + tx] = __float2bfloat16(tile[tx][ty + i*8]);
}

// ------------- V transpose: [BH][T][64] -> [BH][64][T] (bf16) -------------
__global__ __launch_bounds__(256) void vtrans_kernel(
    const bf16* __restrict__ src, bf16* __restrict__ dst)
{
  __shared__ bf16 tile[64][65];
  int bh = blockIdx.x >> 4, t0 = (blockIdx.x & 15) * 64;
  const bf16* s = src + ((size_t)bh * TT + t0) * 64;
  for (int i = 0; i < 16; i++) {
    int idx = threadIdx.x + i*256;
    tile[idx >> 6][idx & 63] = s[idx];
  }
  __syncthreads();
  bf16* o = dst + (size_t)bh * 64 * TT + t0;
  for (int i = 0; i < 16; i++) {
    int idx = threadIdx.x + i*256;
    int d = idx >> 6, t = idx & 63;
    o[(size_t)d * TT + t] = tile[t][d];
  }
}

// ------------- GEMM: C[M,N] = A_bf16[M,K] * Bt_bf16[N,K]^T + bias, fused epilogues -------------
// Register-staged double-buffered K-loop (vmcnt wait lands after MFMAs;
// lgkm-only barrier, no vmcnt drain). Tile 128 x BN, BN in {128, 64}:
// BN=64 halves acc regs + LDS/block -> ~2x blocks/CU for latency hiding,
// at identical total LDS read traffic. XCD band swizzle keeps A panels
// L2-resident per XCD.
template<int EPI, int BN>
__global__ __launch_bounds__(256) void gemm_bt(
    const bf16* __restrict__ A, const bf16* __restrict__ Bt,
    const float* __restrict__ bias, int Mdim, int Ndim, int Kdim,
    const float* __restrict__ res, void* __restrict__ out0,
    bf16* __restrict__ outK, bf16* __restrict__ outV)
{
  constexpr int NJ = BN / 32;          // 16-col tiles per wave (4 or 2)
  __shared__ bf16 As[2][128*32];
  __shared__ bf16 Bs[2][BN*32];
  int tid = threadIdx.x;
  int wave = tid >> 6, lane = tid & 63;
  int quad = lane >> 4, l15 = lane & 15;
  int wr = wave >> 1, wc = wave & 1;

  int Nb = gridDim.x;
  int lin = blockIdx.y * Nb + blockIdx.x;
  int band = lin / (8*Nb);
  int rem  = lin - band*8*Nb;
  int m0 = (band*8 + (rem & 7)) * 128;
  int n0 = (rem >> 3) * BN;

  const int sub = lane >> 2;       // 0..15
  const int kk = (lane & 3) * 8;

  f32x4 acc[4][NJ];
  for (int i = 0; i < 4; i++) for (int j = 0; j < NJ; j++)
    acc[i][j] = (f32x4){0.f,0.f,0.f,0.f};

  // staging pointers: A rows seg0 = wave, seg1 = 4+wave; B rows (BN) by wave
  const bf16* pa0 = A  + (size_t)(m0 + wave*16      + sub)*Kdim + kk;
  const bf16* pa1 = A  + (size_t)(m0 + (4+wave)*16  + sub)*Kdim + kk;
  const bf16* pb0 = Bt + (size_t)(n0 + wave*16      + sub)*Kdim + kk;
  const bf16* pb1 = (BN == 128)
      ? Bt + (size_t)(n0 + (4+wave)*16 + sub)*Kdim + kk : pb0;
  const int woff0 = wave*512     + lane*8;   // bf16 units
  const int woff1 = (4+wave)*512 + lane*8;

  const int niter = Kdim >> 5;

  // prologue: tile 0 -> regs -> buf 0
  bf16x8 ra0 = *reinterpret_cast<const bf16x8*>(pa0);
  bf16x8 ra1 = *reinterpret_cast<const bf16x8*>(pa1);
  bf16x8 rb0 = *reinterpret_cast<const bf16x8*>(pb0);
  bf16x8 rb1;
  if (BN == 128) rb1 = *reinterpret_cast<const bf16x8*>(pb1);
  pa0 += 32; pa1 += 32; pb0 += 32; pb1 += 32;
  *reinterpret_cast<bf16x8*>(As[0] + woff0) = ra0;
  *reinterpret_cast<bf16x8*>(As[0] + woff1) = ra1;
  *reinterpret_cast<bf16x8*>(Bs[0] + woff0) = rb0;
  if (BN == 128) *reinterpret_cast<bf16x8*>(Bs[0] + woff1) = rb1;
  lds_barrier();

  for (int it = 0; it < niter; it++) {
    int cur = it & 1, nxt = cur ^ 1;
    bool more = (it + 1 < niter);
    if (more) {
      ra0 = *reinterpret_cast<const bf16x8*>(pa0);
      ra1 = *reinterpret_cast<const bf16x8*>(pa1);
      rb0 = *reinterpret_cast<const bf16x8*>(pb0);
      if (BN == 128) rb1 = *reinterpret_cast<const bf16x8*>(pb1);
      pa0 += 32; pa1 += 32; pb0 += 32; pb1 += 32;
    }
    // compute tile it from buf cur
    bf16x8 bfr[NJ];
    for (int j = 0; j < NJ; j++)
      bfr[j] = *reinterpret_cast<const bf16x8*>(
          Bs[cur] + (wc*(BN/2) + j*16 + l15)*32 + quad*8);
    for (int i = 0; i < 4; i++) {
      bf16x8 af = *reinterpret_cast<const bf16x8*>(As[cur] + (wr*64 + i*16 + l15)*32 + quad*8);
      for (int j = 0; j < NJ; j++)
        acc[i][j] = MFMA16(af, bfr[j], acc[i][j]);
    }
    if (more) {
      // vmcnt wait for ra/rb lands here (after MFMAs) - full-phase overlap
      *reinterpret_cast<bf16x8*>(As[nxt] + woff0) = ra0;
      *reinterpret_cast<bf16x8*>(As[nxt] + woff1) = ra1;
      *reinterpret_cast<bf16x8*>(Bs[nxt] + woff0) = rb0;
      if (BN == 128) *reinterpret_cast<bf16x8*>(Bs[nxt] + woff1) = rb1;
      lds_barrier();   // reads of cur done by all waves; nxt visible
    }
  }

  for (int i = 0; i < 4; i++) {
    for (int j = 0; j < NJ; j++) {
      for (int r = 0; r < 4; r++) {
        int row = m0 + wr*64 + i*16 + quad*4 + r;
        int col = n0 + wc*(BN/2) + j*16 + l15;
        float cv = acc[i][j][r] + bias[col];
        if (EPI == 0) {
          int part = col / 768;
          int cc = col - part*768;
          int h = cc >> 6, d = cc & 63;
          int b = row >> 10, t = row & 1023;
          bf16* dst = (part == 0) ? (bf16*)out0 : (part == 1) ? outK : outV;
          dst[(((size_t)(b*HH + h))*TT + t)*64 + d] = __float2bfloat16(cv);
        } else if (EPI == 1) {
          ((float*)out0)[(size_t)row*Ndim + col] = cv + res[(size_t)row*Ndim + col];
        } else {
          float u = cv;
          float y = 0.7978845608f*(u + 0.044715f*u*u*u);
          float e = __expf(2.f*fabsf(y));
          float z = 2.f/(e + 1.f);                  // 1 - tanh(|y|)
          float sel = (y >= 0.f) ? (2.f - z) : z;   // 1 + tanh(y)
          ((bf16*)out0)[(size_t)row*Ndim + col] = __float2bfloat16(0.5f*u*sel);
        }
      }
    }
  }
}

// ------------- flash attention with LDS-staged K/V -------------
__global__ __launch_bounds__(256) void attn_kernel(
    const bf16* __restrict__ Q, const bf16* __restrict__ Kb,
    const bf16* __restrict__ Vt, bf16* __restrict__ ctx)
{
  __shared__ bf16 Ks[64*64];      // [key][d], swizzled
  __shared__ bf16 Vs[64*64];      // [d][key], swizzled
  __shared__ bf16 Ps[4*16*64];    // per-wave [q][key], q-swizzled

  int tid = threadIdx.x, wave = tid >> 6, lane = tid & 63;
  int quad = lane >> 4, l15 = lane & 15;
  int bh = blockIdx.x >> 4;
  int tile = 15 - (blockIdx.x & 15);          // heavy tiles first
  int q0b = tile*64;
  int q0w = q0b + wave*16;
  int b = bh / HH, h = bh - b*HH;
  const bf16* Qp = Q + ((size_t)bh*TT + q0w)*64;
  const bf16* Kp = Kb + (size_t)bh*TT*64;
  const bf16* Vp = Vt + (size_t)bh*64*TT;
  bf16* Pw = Ps + wave*16*64;

  bf16x8 qf[2];
  qf[0] = *reinterpret_cast<const bf16x8*>(Qp + l15*64 + quad*8);
  qf[1] = *reinterpret_cast<const bf16x8*>(Qp + l15*64 + 32 + quad*8);

  f32x4 O[4];
  for (int j = 0; j < 4; j++) O[j] = (f32x4){0.f,0.f,0.f,0.f};
  float lsum[4] = {0.f, 0.f, 0.f, 0.f};
  const float c2 = 0.18033688f;   // (1/8) * log2(e)

  const int srow0 = wave*16 + (lane >> 3);   // + rep*8
  const int sc    = lane & 7;                // 16B block within 128B row

  int nc = tile + 1;               // number of 64-key chunks

  bf16x8 kreg[2], vreg[2], kreg2[2], vreg2[2];
  for (int rep = 0; rep < 2; rep++) {
    int row = srow0 + rep*8;
    kreg[rep] = *reinterpret_cast<const bf16x8*>(Kp + (size_t)row*64 + sc*8);
    vreg[rep] = *reinterpret_cast<const bf16x8*>(Vp + (size_t)row*TT + sc*8);
  }

  for (int ci = 0; ci < nc; ci++) {
    int kbase = ci*64;
    __syncthreads();
    for (int rep = 0; rep < 2; rep++) {
      int row = srow0 + rep*8;
      int ph = sc ^ (row & 7);
      *reinterpret_cast<bf16x8*>(Ks + row*64 + ph*8) = kreg[rep];
      *reinterpret_cast<bf16x8*>(Vs + row*64 + ph*8) = vreg[rep];
    }
    if (ci + 1 < nc) {
      int kb2 = kbase + 64;
      for (int rep = 0; rep < 2; rep++) {
        int row = srow0 + rep*8;
        kreg2[rep] = *reinterpret_cast<const bf16x8*>(Kp + (size_t)(kb2 + row)*64 + sc*8);
        vreg2[rep] = *reinterpret_cast<const bf16x8*>(Vp + (size_t)row*TT + kb2 + sc*8);
      }
    }
    __syncthreads();

    f32x4 S[4];
    for (int j = 0; j < 4; j++) S[j] = (f32x4){0.f,0.f,0.f,0.f};
    for (int kh = 0; kh < 2; kh++) {
      for (int j = 0; j < 4; j++) {
        int key = j*16 + l15;
        bf16x8 kf = *reinterpret_cast<const bf16x8*>(
            Ks + key*64 + ((kh*4 + quad) ^ (key & 7))*8);
        S[j] = MFMA16(qf[kh], kf, S[j]);
      }
    }

    float p[4][4];
    if (kbase + 63 > q0w) {
      for (int j = 0; j < 4; j++) {
        int key = kbase + j*16 + l15;
        for (int r = 0; r < 4; r++) {
          int row = q0w + quad*4 + r;
          p[j][r] = (key <= row) ? __builtin_amdgcn_exp2f(S[j][r]*c2) : 0.f;
        }
      }
    } else {
      for (int j = 0; j < 4; j++)
        for (int r = 0; r < 4; r++)
          p[j][r] = __builtin_amdgcn_exp2f(S[j][r]*c2);
    }
    for (int j = 0; j < 4; j++)
      for (int r = 0; r < 4; r++) lsum[r] += p[j][r];

    for (int j = 0; j < 4; j++) {
      int cblk = j*2 + (l15 >> 3);
      int koff = l15 & 7;
      for (int r = 0; r < 4; r++) {
        int q = quad*4 + r;
        Pw[q*64 + (cblk ^ (q & 7))*8 + koff] = __float2bfloat16(p[j][r]);
      }
    }

    for (int kh = 0; kh < 2; kh++) {
      bf16x8 pf = *reinterpret_cast<const bf16x8*>(
          Pw + l15*64 + ((kh*4 + quad) ^ (l15 & 7))*8);
      for (int j = 0; j < 4; j++) {
        int d = j*16 + l15;
        bf16x8 vf = *reinterpret_cast<const bf16x8*>(
            Vs + d*64 + ((kh*4 + quad) ^ (d & 7))*8);
        O[j] = MFMA16(pf, vf, O[j]);
      }
    }

    for (int rep = 0; rep < 2; rep++) { kreg[rep] = kreg2[rep]; vreg[rep] = vreg2[rep]; }
  }

  for (int r = 0; r < 4; r++)
    for (int msk = 1; msk < 16; msk <<= 1)
      lsum[r] += __shfl_xor(lsum[r], msk);

  bf16* cp = ctx + ((size_t)b*TT + q0w)*CC + h*64;
  for (int r = 0; r < 4; r++) {
    float inv = 1.f / lsum[r];
    int row = quad*4 + r;
    for (int j = 0; j < 4; j++)
      cp[(size_t)row*CC + j*16 + l15] = __float2bfloat16(O[j][r]*inv);
  }
}

extern "C" void kernel_launch(void* const* d_in, const int* in_sizes, int n_in,
                              void* d_out, int out_size, void* d_ws, size_t ws_size,
                              hipStream_t stream)
{
  const float* x    = (const float*)d_in[0];
  const float* ln1s = (const float*)d_in[2];
  const float* ln1b = (const float*)d_in[3];
  const float* wqkv = (const float*)d_in[4];
  const float* bqkv = (const float*)d_in[5];
  const float* wap  = (const float*)d_in[6];
  const float* bap  = (const float*)d_in[7];
  const float* ln2s = (const float*)d_in[8];
  const float* ln2b = (const float*)d_in[9];
  const float* wfc  = (const float*)d_in[10];
  const float* bfc  = (const float*)d_in[11];
  const float* wmp  = (const float*)d_in[12];
  const float* bmp  = (const float*)d_in[13];

  char* ws = (char*)d_ws;
  bf16* wqkv_t = (bf16*)ws; ws += (size_t)2304*768*2;
  bf16* wap_t  = (bf16*)ws; ws += (size_t)768*768*2;
  bf16* wfc_t  = (bf16*)ws; ws += (size_t)3072*768*2;
  bf16* wmp_t  = (bf16*)ws; ws += (size_t)768*3072*2;
  bf16* buf1   = (bf16*)ws; ws += (size_t)MROWS*CC*2;   // h / ctx / h2
  bf16* Qb     = (bf16*)ws; ws += (size_t)MROWS*CC*2;
  bf16* Kbuf   = (bf16*)ws; ws += (size_t)MROWS*CC*2;
  bf16* Vb     = (bf16*)ws; ws += (size_t)MROWS*CC*2;
  bf16* Vt     = (bf16*)ws; ws += (size_t)MROWS*CC*2;
  bf16* g      = Qb;  // reuse Q/K/V/Vt region for [8192][3072] bf16
  float* r1    = (float*)ws; ws += (size_t)MROWS*CC*4;

  dim3 blk(256);
  wtrans_kernel<<<dim3(2304/32, 768/32), blk, 0, stream>>>(wqkv, wqkv_t, 768, 2304);
  wtrans_kernel<<<dim3(768/32, 768/32), blk, 0, stream>>>(wap, wap_t, 768, 768);
  wtrans_kernel<<<dim3(3072/32, 768/32), blk, 0, stream>>>(wfc, wfc_t, 768, 3072);
  wtrans_kernel<<<dim3(768/32, 3072/32), blk, 0, stream>>>(wmp, wmp_t, 3072, 768);
  ln_kernel<<<MROWS, blk, 0, stream>>>(x, ln1s, ln1b, buf1);
  gemm_bt<0,64><<<dim3(2304/64, MROWS/128), blk, 0, stream>>>(
      buf1, wqkv_t, bqkv, MROWS, 2304, 768, nullptr, (void*)Qb, Kbuf, Vb);
  vtrans_kernel<<<BB*HH*16, blk, 0, stream>>>(Vb, Vt);
  attn_kernel<<<BB*HH*16, blk, 0, stream>>>(Qb, Kbuf, Vt, buf1);
  gemm_bt<1,64><<<dim3(768/64, MROWS/128), blk, 0, stream>>>(
      buf1, wap_t, bap, MROWS, 768, 768, x, (void*)r1, nullptr, nullptr);
  ln_kernel<<<MROWS, blk, 0, stream>>>(r1, ln2s, ln2b, buf1);
  gemm_bt<2,64><<<dim3(3072/64, MROWS/128), blk, 0, stream>>>(
      buf1, wfc_t, bfc, MROWS, 3072, 768, nullptr, (void*)g, nullptr, nullptr);
  gemm_bt<1,64><<<dim3(768/64, MROWS/128), blk, 0, stream>>>(
      g, wmp_t, bmp, MROWS, 768, 3072, r1, d_out, nullptr, nullptr);
}

// Round 8
// 397.230 us; speedup vs baseline: 1.0410x; 1.0410x over previous
//
#include <hip/hip_runtime.h>
#include <hip/hip_bf16.h>
#include <cstdint>
#include <math.h>

// Problem dims
#define BB 8
#define TT 1024
#define CC 768
#define HH 12
#define MROWS (BB*TT)   // 8192

typedef __hip_bfloat16 bf16;
typedef __attribute__((ext_vector_type(8))) __bf16 bf16x8;
typedef __attribute__((ext_vector_type(4))) float f32x4;

#define MFMA16(a,b,c) __builtin_amdgcn_mfma_f32_16x16x32_bf16(a,b,c,0,0,0)

// lgkm-only barrier: legal because the only outstanding vmem ops at the
// barrier are private register loads (not observable cross-thread). Avoids
// the compiler's s_waitcnt vmcnt(0) drain at __syncthreads.
__device__ __forceinline__ void lds_barrier() {
  asm volatile("s_waitcnt lgkmcnt(0)\n\ts_barrier" ::: "memory");
}

// ---------------- LayerNorm: f32 [rows][768] -> bf16 ----------------
__global__ __launch_bounds__(256) void ln_kernel(
    const float* __restrict__ x, const float* __restrict__ scale,
    const float* __restrict__ bias, bf16* __restrict__ out)
{
  int row = blockIdx.x;
  const float* xr = x + (size_t)row * CC;
  float v[3];
  float s = 0.f, s2 = 0.f;
  for (int i = 0; i < 3; i++) {
    v[i] = xr[threadIdx.x + i*256];
    s += v[i]; s2 += v[i]*v[i];
  }
  for (int m = 1; m < 64; m <<= 1) { s += __shfl_xor(s, m); s2 += __shfl_xor(s2, m); }
  __shared__ float ssum[4], ssum2[4];
  int w = threadIdx.x >> 6;
  if ((threadIdx.x & 63) == 0) { ssum[w] = s; ssum2[w] = s2; }
  __syncthreads();
  s = ssum[0]+ssum[1]+ssum[2]+ssum[3];
  s2 = ssum2[0]+ssum2[1]+ssum2[2]+ssum2[3];
  float mu = s * (1.f/CC);
  float var = s2 * (1.f/CC) - mu*mu;
  float rs = rsqrtf(var + 1e-5f);
  bf16* orow = out + (size_t)row * CC;
  for (int i = 0; i < 3; i++) {
    int c = threadIdx.x + i*256;
    orow[c] = __float2bfloat16((v[i]-mu)*rs*scale[c] + bias[c]);
  }
}

// ------------- weight transpose-cast: src f32 [K][N] -> dst bf16 [N][K] -------------
__global__ __launch_bounds__(256) void wtrans_kernel(
    const float* __restrict__ src, bf16* __restrict__ dst, int K, int N)
{
  __shared__ float tile[32][33];
  int n0 = blockIdx.x * 32, k0 = blockIdx.y * 32;
  int tx = threadIdx.x & 31, ty = threadIdx.x >> 5;   // ty 0..7
  for (int i = 0; i < 4; i++)
    tile[ty + i*8][tx] = src[(size_t)(k0 + ty + i*8)*N + n0 + tx];
  __syncthreads();
  for (int i = 0; i < 4; i++)
    dst[(size_t)(n0 + ty + i*8)*K + k0 + tx] = __float2bfloat16(tile[tx][ty + i*8]);
}

// ------------- V transpose: [BH][T][64] -> [BH][64][T] (bf16) -------------
__global__ __launch_bounds__(256) void vtrans_kernel(
    const bf16* __restrict__ src, bf16* __restrict__ dst)
{
  __shared__ bf16 tile[64][65];
  int bh = blockIdx.x >> 4, t0 = (blockIdx.x & 15) * 64;
  const bf16* s = src + ((size_t)bh * TT + t0) * 64;
  for (int i = 0; i < 16; i++) {
    int idx = threadIdx.x + i*256;
    tile[idx >> 6][idx & 63] = s[idx];
  }
  __syncthreads();
  bf16* o = dst + (size_t)bh * 64 * TT + t0;
  for (int i = 0; i < 16; i++) {
    int idx = threadIdx.x + i*256;
    int d = idx >> 6, t = idx & 63;
    o[(size_t)d * TT + t] = tile[t][d];
  }
}

// ------------- GEMM: C[M,N] = A_bf16[M,K] * Bt_bf16[N,K]^T + bias, fused epilogues -------------
// Register-staged double-buffered K-loop (vmcnt wait lands after MFMAs;
// lgkm-only barrier, no vmcnt drain). 128x128 tile. LDS tiles use a 16B
// XOR swizzle: element (row, kblk) at row*32 + (kblk ^ ((row>>1)&3))*8 so
// each quad's 16-lane fragment read spreads over all 32 banks (2 lanes per
// 4-bank group = free) instead of 8 banks (4-way conflict). XCD band
// swizzle keeps A panels L2-resident per XCD.
template<int EPI>
__global__ __launch_bounds__(256) void gemm_bt(
    const bf16* __restrict__ A, const bf16* __restrict__ Bt,
    const float* __restrict__ bias, int Mdim, int Ndim, int Kdim,
    const float* __restrict__ res, void* __restrict__ out0,
    bf16* __restrict__ outK, bf16* __restrict__ outV)
{
  __shared__ bf16 As[2][128*32];
  __shared__ bf16 Bs[2][128*32];
  int tid = threadIdx.x;
  int wave = tid >> 6, lane = tid & 63;
  int quad = lane >> 4, l15 = lane & 15;
  int wr = wave >> 1, wc = wave & 1;

  int Nb = gridDim.x;
  int lin = blockIdx.y * Nb + blockIdx.x;
  int band = lin / (8*Nb);
  int rem  = lin - band*8*Nb;
  int m0 = (band*8 + (rem & 7)) * 128;
  int n0 = (rem >> 3) * 128;

  const int sub = lane >> 2;       // 0..15 (row within 16-row segment)
  const int kk = (lane & 3) * 8;   // k-block for staging load

  f32x4 acc[4][4];
  for (int i = 0; i < 4; i++) for (int j = 0; j < 4; j++)
    acc[i][j] = (f32x4){0.f,0.f,0.f,0.f};

  // staging pointers: seg0 = wave (rows 0..63), seg1 = 4+wave (rows 64..127)
  const bf16* pa0 = A  + (size_t)(m0 + wave*16      + sub)*Kdim + kk;
  const bf16* pa1 = A  + (size_t)(m0 + (4+wave)*16  + sub)*Kdim + kk;
  const bf16* pb0 = Bt + (size_t)(n0 + wave*16      + sub)*Kdim + kk;
  const bf16* pb1 = Bt + (size_t)(n0 + (4+wave)*16  + sub)*Kdim + kk;
  // swizzled write offsets (bf16 units): row*32 + (kblk ^ ((row>>1)&3))*8
  // row = seg*16 + (lane>>2) -> (row>>1)&3 == (lane>>3)&3 (seg*8 mod 4 == 0)
  const int pblk  = ((lane & 3) ^ ((lane >> 3) & 3));
  const int woff0 = (wave*16     + sub)*32 + pblk*8;
  const int woff1 = ((4+wave)*16 + sub)*32 + pblk*8;
  // swizzled read block position: quad ^ ((l15>>1)&3)  (row base mult of 16)
  const int rblk  = (quad ^ ((l15 >> 1) & 3)) * 8;

  const int niter = Kdim >> 5;

  // prologue: tile 0 -> regs -> buf 0
  bf16x8 ra0 = *reinterpret_cast<const bf16x8*>(pa0);
  bf16x8 ra1 = *reinterpret_cast<const bf16x8*>(pa1);
  bf16x8 rb0 = *reinterpret_cast<const bf16x8*>(pb0);
  bf16x8 rb1 = *reinterpret_cast<const bf16x8*>(pb1);
  pa0 += 32; pa1 += 32; pb0 += 32; pb1 += 32;
  *reinterpret_cast<bf16x8*>(As[0] + woff0) = ra0;
  *reinterpret_cast<bf16x8*>(As[0] + woff1) = ra1;
  *reinterpret_cast<bf16x8*>(Bs[0] + woff0) = rb0;
  *reinterpret_cast<bf16x8*>(Bs[0] + woff1) = rb1;
  lds_barrier();

  for (int it = 0; it < niter; it++) {
    int cur = it & 1, nxt = cur ^ 1;
    bool more = (it + 1 < niter);
    if (more) {
      ra0 = *reinterpret_cast<const bf16x8*>(pa0);
      ra1 = *reinterpret_cast<const bf16x8*>(pa1);
      rb0 = *reinterpret_cast<const bf16x8*>(pb0);
      rb1 = *reinterpret_cast<const bf16x8*>(pb1);
      pa0 += 32; pa1 += 32; pb0 += 32; pb1 += 32;
    }
    // compute tile it from buf cur
    bf16x8 bfr[4];
    for (int j = 0; j < 4; j++)
      bfr[j] = *reinterpret_cast<const bf16x8*>(Bs[cur] + (wc*64 + j*16 + l15)*32 + rblk);
    for (int i = 0; i < 4; i++) {
      bf16x8 af = *reinterpret_cast<const bf16x8*>(As[cur] + (wr*64 + i*16 + l15)*32 + rblk);
      for (int j = 0; j < 4; j++)
        acc[i][j] = MFMA16(af, bfr[j], acc[i][j]);
    }
    if (more) {
      // vmcnt wait for ra/rb lands here (after MFMAs) - full-phase overlap
      *reinterpret_cast<bf16x8*>(As[nxt] + woff0) = ra0;
      *reinterpret_cast<bf16x8*>(As[nxt] + woff1) = ra1;
      *reinterpret_cast<bf16x8*>(Bs[nxt] + woff0) = rb0;
      *reinterpret_cast<bf16x8*>(Bs[nxt] + woff1) = rb1;
      lds_barrier();   // reads of cur done by all waves; nxt visible
    }
  }

  for (int i = 0; i < 4; i++) {
    for (int j = 0; j < 4; j++) {
      for (int r = 0; r < 4; r++) {
        int row = m0 + wr*64 + i*16 + quad*4 + r;
        int col = n0 + wc*64 + j*16 + l15;
        float cv = acc[i][j][r] + bias[col];
        if (EPI == 0) {
          int part = col / 768;
          int cc = col - part*768;
          int h = cc >> 6, d = cc & 63;
          int b = row >> 10, t = row & 1023;
          bf16* dst = (part == 0) ? (bf16*)out0 : (part == 1) ? outK : outV;
          dst[(((size_t)(b*HH + h))*TT + t)*64 + d] = __float2bfloat16(cv);
        } else if (EPI == 1) {
          ((float*)out0)[(size_t)row*Ndim + col] = cv + res[(size_t)row*Ndim + col];
        } else {
          float u = cv;
          float y = 0.7978845608f*(u + 0.044715f*u*u*u);
          float e = __expf(2.f*fabsf(y));
          float z = 2.f/(e + 1.f);                  // 1 - tanh(|y|)
          float sel = (y >= 0.f) ? (2.f - z) : z;   // 1 + tanh(y)
          ((bf16*)out0)[(size_t)row*Ndim + col] = __float2bfloat16(0.5f*u*sel);
        }
      }
    }
  }
}

// ------------- flash attention with LDS-staged K/V -------------
__global__ __launch_bounds__(256) void attn_kernel(
    const bf16* __restrict__ Q, const bf16* __restrict__ Kb,
    const bf16* __restrict__ Vt, bf16* __restrict__ ctx)
{
  __shared__ bf16 Ks[64*64];      // [key][d], swizzled
  __shared__ bf16 Vs[64*64];      // [d][key], swizzled
  __shared__ bf16 Ps[4*16*64];    // per-wave [q][key], q-swizzled

  int tid = threadIdx.x, wave = tid >> 6, lane = tid & 63;
  int quad = lane >> 4, l15 = lane & 15;
  int bh = blockIdx.x >> 4;
  int tile = 15 - (blockIdx.x & 15);          // heavy tiles first
  int q0b = tile*64;
  int q0w = q0b + wave*16;
  int b = bh / HH, h = bh - b*HH;
  const bf16* Qp = Q + ((size_t)bh*TT + q0w)*64;
  const bf16* Kp = Kb + (size_t)bh*TT*64;
  const bf16* Vp = Vt + (size_t)bh*64*TT;
  bf16* Pw = Ps + wave*16*64;

  bf16x8 qf[2];
  qf[0] = *reinterpret_cast<const bf16x8*>(Qp + l15*64 + quad*8);
  qf[1] = *reinterpret_cast<const bf16x8*>(Qp + l15*64 + 32 + quad*8);

  f32x4 O[4];
  for (int j = 0; j < 4; j++) O[j] = (f32x4){0.f,0.f,0.f,0.f};
  float lsum[4] = {0.f, 0.f, 0.f, 0.f};
  const float c2 = 0.18033688f;   // (1/8) * log2(e)

  const int srow0 = wave*16 + (lane >> 3);   // + rep*8
  const int sc    = lane & 7;                // 16B block within 128B row

  int nc = tile + 1;               // number of 64-key chunks

  bf16x8 kreg[2], vreg[2], kreg2[2], vreg2[2];
  for (int rep = 0; rep < 2; rep++) {
    int row = srow0 + rep*8;
    kreg[rep] = *reinterpret_cast<const bf16x8*>(Kp + (size_t)row*64 + sc*8);
    vreg[rep] = *reinterpret_cast<const bf16x8*>(Vp + (size_t)row*TT + sc*8);
  }

  for (int ci = 0; ci < nc; ci++) {
    int kbase = ci*64;
    __syncthreads();
    for (int rep = 0; rep < 2; rep++) {
      int row = srow0 + rep*8;
      int ph = sc ^ (row & 7);
      *reinterpret_cast<bf16x8*>(Ks + row*64 + ph*8) = kreg[rep];
      *reinterpret_cast<bf16x8*>(Vs + row*64 + ph*8) = vreg[rep];
    }
    if (ci + 1 < nc) {
      int kb2 = kbase + 64;
      for (int rep = 0; rep < 2; rep++) {
        int row = srow0 + rep*8;
        kreg2[rep] = *reinterpret_cast<const bf16x8*>(Kp + (size_t)(kb2 + row)*64 + sc*8);
        vreg2[rep] = *reinterpret_cast<const bf16x8*>(Vp + (size_t)row*TT + kb2 + sc*8);
      }
    }
    __syncthreads();

    f32x4 S[4];
    for (int j = 0; j < 4; j++) S[j] = (f32x4){0.f,0.f,0.f,0.f};
    for (int kh = 0; kh < 2; kh++) {
      for (int j = 0; j < 4; j++) {
        int key = j*16 + l15;
        bf16x8 kf = *reinterpret_cast<const bf16x8*>(
            Ks + key*64 + ((kh*4 + quad) ^ (key & 7))*8);
        S[j] = MFMA16(qf[kh], kf, S[j]);
      }
    }

    float p[4][4];
    if (kbase + 63 > q0w) {
      for (int j = 0; j < 4; j++) {
        int key = kbase + j*16 + l15;
        for (int r = 0; r < 4; r++) {
          int row = q0w + quad*4 + r;
          p[j][r] = (key <= row) ? __builtin_amdgcn_exp2f(S[j][r]*c2) : 0.f;
        }
      }
    } else {
      for (int j = 0; j < 4; j++)
        for (int r = 0; r < 4; r++)
          p[j][r] = __builtin_amdgcn_exp2f(S[j][r]*c2);
    }
    for (int j = 0; j < 4; j++)
      for (int r = 0; r < 4; r++) lsum[r] += p[j][r];

    for (int j = 0; j < 4; j++) {
      int cblk = j*2 + (l15 >> 3);
      int koff = l15 & 7;
      for (int r = 0; r < 4; r++) {
        int q = quad*4 + r;
        Pw[q*64 + (cblk ^ (q & 7))*8 + koff] = __float2bfloat16(p[j][r]);
      }
    }

    for (int kh = 0; kh < 2; kh++) {
      bf16x8 pf = *reinterpret_cast<const bf16x8*>(
          Pw + l15*64 + ((kh*4 + quad) ^ (l15 & 7))*8);
      for (int j = 0; j < 4; j++) {
        int d = j*16 + l15;
        bf16x8 vf = *reinterpret_cast<const bf16x8*>(
            Vs + d*64 + ((kh*4 + quad) ^ (d & 7))*8);
        O[j] = MFMA16(pf, vf, O[j]);
      }
    }

    for (int rep = 0; rep < 2; rep++) { kreg[rep] = kreg2[rep]; vreg[rep] = vreg2[rep]; }
  }

  for (int r = 0; r < 4; r++)
    for (int msk = 1; msk < 16; msk <<= 1)
      lsum[r] += __shfl_xor(lsum[r], msk);

  bf16* cp = ctx + ((size_t)b*TT + q0w)*CC + h*64;
  for (int r = 0; r < 4; r++) {
    float inv = 1.f / lsum[r];
    int row = quad*4 + r;
    for (int j = 0; j < 4; j++)
      cp[(size_t)row*CC + j*16 + l15] = __float2bfloat16(O[j][r]*inv);
  }
}

extern "C" void kernel_launch(void* const* d_in, const int* in_sizes, int n_in,
                              void* d_out, int out_size, void* d_ws, size_t ws_size,
                              hipStream_t stream)
{
  const float* x    = (const float*)d_in[0];
  const float* ln1s = (const float*)d_in[2];
  const float* ln1b = (const float*)d_in[3];
  const float* wqkv = (const float*)d_in[4];
  const float* bqkv = (const float*)d_in[5];
  const float* wap  = (const float*)d_in[6];
  const float* bap  = (const float*)d_in[7];
  const float* ln2s = (const float*)d_in[8];
  const float* ln2b = (const float*)d_in[9];
  const float* wfc  = (const float*)d_in[10];
  const float* bfc  = (const float*)d_in[11];
  const float* wmp  = (const float*)d_in[12];
  const float* bmp  = (const float*)d_in[13];

  char* ws = (char*)d_ws;
  bf16* wqkv_t = (bf16*)ws; ws += (size_t)2304*768*2;
  bf16* wap_t  = (bf16*)ws; ws += (size_t)768*768*2;
  bf16* wfc_t  = (bf16*)ws; ws += (size_t)3072*768*2;
  bf16* wmp_t  = (bf16*)ws; ws += (size_t)768*3072*2;
  bf16* buf1   = (bf16*)ws; ws += (size_t)MROWS*CC*2;   // h / ctx / h2
  bf16* Qb     = (bf16*)ws; ws += (size_t)MROWS*CC*2;
  bf16* Kbuf   = (bf16*)ws; ws += (size_t)MROWS*CC*2;
  bf16* Vb     = (bf16*)ws; ws += (size_t)MROWS*CC*2;
  bf16* Vt     = (bf16*)ws; ws += (size_t)MROWS*CC*2;
  bf16* g      = Qb;  // reuse Q/K/V/Vt region for [8192][3072] bf16
  float* r1    = (float*)ws; ws += (size_t)MROWS*CC*4;

  dim3 blk(256);
  wtrans_kernel<<<dim3(2304/32, 768/32), blk, 0, stream>>>(wqkv, wqkv_t, 768, 2304);
  wtrans_kernel<<<dim3(768/32, 768/32), blk, 0, stream>>>(wap, wap_t, 768, 768);
  wtrans_kernel<<<dim3(3072/32, 768/32), blk, 0, stream>>>(wfc, wfc_t, 768, 3072);
  wtrans_kernel<<<dim3(768/32, 3072/32), blk, 0, stream>>>(wmp, wmp_t, 3072, 768);
  ln_kernel<<<MROWS, blk, 0, stream>>>(x, ln1s, ln1b, buf1);
  gemm_bt<0><<<dim3(2304/128, MROWS/128), blk, 0, stream>>>(
      buf1, wqkv_t, bqkv, MROWS, 2304, 768, nullptr, (void*)Qb, Kbuf, Vb);
  vtrans_kernel<<<BB*HH*16, blk, 0, stream>>>(Vb, Vt);
  attn_kernel<<<BB*HH*16, blk, 0, stream>>>(Qb, Kbuf, Vt, buf1);
  gemm_bt<1><<<dim3(768/128, MROWS/128), blk, 0, stream>>>(
      buf1, wap_t, bap, MROWS, 768, 768, x, (void*)r1, nullptr, nullptr);
  ln_kernel<<<MROWS, blk, 0, stream>>>(r1, ln2s, ln2b, buf1);
  gemm_bt<2><<<dim3(3072/128, MROWS/128), blk, 0, stream>>>(
      buf1, wfc_t, bfc, MROWS, 3072, 768, nullptr, (void*)g, nullptr, nullptr);
  gemm_bt<1><<<dim3(768/128, MROWS/128), blk, 0, stream>>>(
      g, wmp_t, bmp, MROWS, 768, 3072, r1, d_out, nullptr, nullptr);
}